// Round 1
// 1198.718 us; speedup vs baseline: 1.0579x; 1.0579x over previous
//
#include <hip/hip_runtime.h>
#include <math.h>

#define TAU 0.07f
#define B_ 8
#define C_ 128
#define HW_ (512 * 512)
#define K_ 64
#define NNEG_ 7
#define P_ 4096

__device__ inline float wave_reduce_sum(float v) {
    #pragma unroll
    for (int off = 32; off; off >>= 1) v += __shfl_xor(v, off, 64);
    return v;
}

__device__ inline unsigned long long wave_reduce_maxu64(unsigned long long v) {
    #pragma unroll
    for (int off = 32; off; off >>= 1) {
        unsigned long long o = __shfl_xor(v, off, 64);
        v = (o > v) ? o : v;
    }
    return v;
}

// One block (128 threads) per prototype: L2-normalize pos_pool rows and store
// TRANSPOSED into poolT[c * P + p], so the argmax kernel reads lane-consecutive
// prototypes (fully coalesced 1 KB bursts instead of 512B-strided gathers).
__global__ void normalize_transpose_kernel(const float* __restrict__ pool,
                                           float* __restrict__ poolT) {
    const int p = blockIdx.x;
    const int c = threadIdx.x;  // 128 threads
    __shared__ float red[2];
    float v = pool[p * C_ + c];
    float ws = wave_reduce_sum(v * v);
    if ((c & 63) == 0) red[c >> 6] = ws;
    __syncthreads();
    const float inv = 1.0f / fmaxf(sqrtf(red[0] + red[1]), 1e-12f);
    // scattered 4B stores (stride 16 KB between lanes): ~0.5M transactions
    // total, ~2 us across the chip -- acceptable for a 2 MB transpose.
    poolT[(size_t)c * P_ + p] = v * inv;
}

// One block (256 threads) per (b,k) query.
__global__ void __launch_bounds__(256)
loss_kernel(const float* __restrict__ qf,     // [B, C, HW]
            const float* __restrict__ poolT,  // [C, P] normalized, transposed
            const float* __restrict__ neg,    // [B, K, N, C]
            const int* __restrict__ qidx,     // [B, K]
            float* __restrict__ out) {
    const int bk = blockIdx.x;       // b*K + k
    const int b = bk >> 6;           // / K_
    const int t = threadIdx.x;
    const int wid = t >> 6;
    const int lane = t & 63;

    __shared__ __align__(16) float qn[C_];
    __shared__ float red[4];
    __shared__ float lgsh[1 + NNEG_];
    __shared__ unsigned long long redk[4];

    // ---- gather query pixel and L2-normalize ----
    const int idx = qidx[bk];
    float v = 0.0f;
    if (t < C_) v = qf[((size_t)b * C_ + t) * (size_t)HW_ + idx];
    {
        float ws = wave_reduce_sum(v * v);
        if (lane == 0) red[wid] = ws;  // waves 2,3 contribute 0
    }
    __syncthreads();
    const float qss = red[0] + red[1] + red[2] + red[3];
    const float qinv = 1.0f / fmaxf(sqrtf(qss), 1e-12f);
    if (t < C_) qn[t] = v * qinv;
    __syncthreads();

    // ---- argmax over P prototypes, coalesced via transposed pool ----
    // Thread t, pass j owns prototypes p = 4*(j*256+t) .. +3; one float4 load
    // delivers 4 consecutive p at fixed c, lanes consecutive -> 1 KB bursts.
    const float4* __restrict__ pT4 = (const float4*)poolT;  // [C_][P_/4]
    const float4* qn4 = (const float4*)qn;
    float best = -3.0e38f;
    int bestp = 0;
    #pragma unroll 1
    for (int j = 0; j < P_ / 1024; ++j) {  // 4 passes
        float4 d; d.x = 0.0f; d.y = 0.0f; d.z = 0.0f; d.w = 0.0f;
        const float4* __restrict__ col = pT4 + (size_t)j * 256 + t;
        #pragma unroll 4
        for (int cc = 0; cc < C_ / 4; ++cc) {
            const float4 qv = qn4[cc];
            const float4 v0 = col[(size_t)(4 * cc + 0) * (P_ / 4)];
            const float4 v1 = col[(size_t)(4 * cc + 1) * (P_ / 4)];
            const float4 v2 = col[(size_t)(4 * cc + 2) * (P_ / 4)];
            const float4 v3 = col[(size_t)(4 * cc + 3) * (P_ / 4)];
            d.x += qv.x * v0.x + qv.y * v1.x + qv.z * v2.x + qv.w * v3.x;
            d.y += qv.x * v0.y + qv.y * v1.y + qv.z * v2.y + qv.w * v3.y;
            d.z += qv.x * v0.z + qv.y * v1.z + qv.z * v2.z + qv.w * v3.z;
            d.w += qv.x * v0.w + qv.y * v1.w + qv.z * v2.w + qv.w * v3.w;
        }
        const int pb = (j * 256 + t) * 4;
        // ascending p with strict > keeps the first (lowest) index on ties
        if (d.x > best) { best = d.x; bestp = pb + 0; }
        if (d.y > best) { best = d.y; bestp = pb + 1; }
        if (d.z > best) { best = d.z; bestp = pb + 2; }
        if (d.w > best) { best = d.w; bestp = pb + 3; }
    }
    // pack (value, ~idx) so max-key == (max value, lowest index)
    unsigned int fu = __float_as_uint(best);
    fu = (fu & 0x80000000u) ? ~fu : (fu | 0x80000000u);
    unsigned long long key =
        ((unsigned long long)fu << 32) | (unsigned int)(~(unsigned int)bestp);
    key = wave_reduce_maxu64(key);
    if (lane == 0) redk[wid] = key;

    // ---- negatives: wave w handles n = w, w+4 (wave-local reductions) ----
    const float2* __restrict__ qn2 = (const float2*)qn;
    const float2 q2 = qn2[lane];
    const float2* __restrict__ neg2 =
        (const float2*)(neg + (size_t)bk * NNEG_ * C_);
    for (int n = wid; n < NNEG_; n += 4) {
        const float2 nv = neg2[n * (C_ / 2) + lane];
        float s1 = wave_reduce_sum(nv.x * nv.x + nv.y * nv.y);
        float s2 = wave_reduce_sum(nv.x * q2.x + nv.y * q2.y);
        if (lane == 0)
            lgsh[1 + n] = (s2 / fmaxf(sqrtf(s1), 1e-12f)) * (1.0f / TAU);
    }
    __syncthreads();

    // ---- log-softmax CE, label 0; mean over B*K via atomic ----
    if (t == 0) {
        unsigned long long k2 = redk[0];
        #pragma unroll
        for (int i = 1; i < 4; ++i) k2 = (redk[i] > k2) ? redk[i] : k2;
        unsigned int vu = (unsigned int)(k2 >> 32);
        vu = (vu & 0x80000000u) ? (vu ^ 0x80000000u) : ~vu;
        float lg0 = __uint_as_float(vu) * (1.0f / TAU);  // pos logit
        float m = lg0;
        #pragma unroll
        for (int i = 1; i <= NNEG_; ++i) m = fmaxf(m, lgsh[i]);
        float se = expf(lg0 - m);
        #pragma unroll
        for (int i = 1; i <= NNEG_; ++i) se += expf(lgsh[i] - m);
        const float loss = (m + logf(se)) - lg0;
        atomicAdd(out, loss * (1.0f / (B_ * K_)));
    }
}

extern "C" void kernel_launch(void* const* d_in, const int* in_sizes, int n_in,
                              void* d_out, int out_size, void* d_ws, size_t ws_size,
                              hipStream_t stream) {
    const float* query_feat = (const float*)d_in[0];  // [B, C, H, W] fp32
    const float* pos_pool   = (const float*)d_in[1];  // [P, C] fp32
    const float* neg_protos = (const float*)d_in[2];  // [B, K, N, C] fp32
    const int*   query_idx  = (const int*)d_in[3];    // [B, K] int32
    float* out = (float*)d_out;                       // scalar fp32

    float* poolT = (float*)d_ws;  // P*C floats = 2 MB, [C][P] layout

    hipMemsetAsync(out, 0, sizeof(float) * out_size, stream);
    normalize_transpose_kernel<<<P_, C_, 0, stream>>>(pos_pool, poolT);
    loss_kernel<<<B_ * K_, 256, 0, stream>>>(query_feat, poolT, neg_protos,
                                             query_idx, out);
}